// Round 9
// baseline (221.428 us; speedup 1.0000x reference)
//
#include <hip/hip_runtime.h>
#include <hip/hip_bf16.h>
#include <math.h>

// Problem constants
constexpr int B = 16;
constexpr int S = 2048;
constexpr int H = 1024;
constexpr int E = 2048;

constexpr int QZ = 16;   // hp-split for qw partials
constexpr int UZ = 16;   // h-split for u partials

// ---------------------------------------------------------------------------
// K1: qp[b,h] = dot(query[b,:], W_q[h,:]) for ALL b at once.
// grid 256 blocks x 256 thr; wave per h-row; W_q read exactly once (4 MB).
// query[16][1024] staged in LDS; 16 batch-accumulators per lane.
// ---------------------------------------------------------------------------
__global__ void k_qp(const float* __restrict__ query,
                     const float* __restrict__ W_q,
                     float* __restrict__ qp) {
    __shared__ float4 qs[B * H / 4];      // 64 KB
    int tid = threadIdx.x;
    for (int i = 0; i < B * H / 4; i += 256)
        qs[i + tid] = ((const float4*)query)[i + tid];
    __syncthreads();

    int wave = tid >> 6, lane = tid & 63;
    int h = blockIdx.x * 4 + wave;
    const float4* wrow = (const float4*)(W_q + (size_t)h * H);
    float acc[B];
    #pragma unroll
    for (int b = 0; b < B; ++b) acc[b] = 0.f;
    #pragma unroll
    for (int i = 0; i < 4; ++i) {                  // 256 float4 per row / 64 lanes
        float4 w = wrow[i * 64 + lane];
        #pragma unroll
        for (int b = 0; b < B; ++b) {
            float4 q = qs[b * (H / 4) + i * 64 + lane];
            acc[b] += w.x * q.x + w.y * q.y + w.z * q.z + w.w * q.w;
        }
    }
    #pragma unroll
    for (int off = 32; off; off >>= 1)
        #pragma unroll
        for (int b = 0; b < B; ++b)
            acc[b] += __shfl_down(acc[b], off, 64);
    if (lane == 0) {
        #pragma unroll
        for (int b = 0; b < B; ++b) qp[b * H + h] = acc[b];
    }
}

// ---------------------------------------------------------------------------
// K2: qwp[z][b][h] = sum_{hp in 64-chunk z} qp[b,hp] * W_bil[hp,h], all b.
// grid (H/256=4, QZ=16) = 64 blocks x 256 thr; W_bil read exactly once (4 MB).
// ---------------------------------------------------------------------------
__global__ void k_qw2(const float* __restrict__ qp,
                      const float* __restrict__ W_bil,
                      float* __restrict__ qwp) {
    __shared__ float qpl[B][64];
    int tid = threadIdx.x;
    int z = blockIdx.y;
    for (int k = tid; k < B * 64; k += 256) {
        int b = k >> 6, j = k & 63;
        qpl[b][j] = qp[b * H + z * 64 + j];
    }
    __syncthreads();
    int col = blockIdx.x * 256 + tid;
    float acc[B];
    #pragma unroll
    for (int b = 0; b < B; ++b) acc[b] = 0.f;
    #pragma unroll 8
    for (int j = 0; j < 64; ++j) {
        float w = W_bil[(size_t)(z * 64 + j) * H + col];
        #pragma unroll
        for (int b = 0; b < B; ++b) acc[b] += qpl[b][j] * w;
    }
    #pragma unroll
    for (int b = 0; b < B; ++b)
        qwp[((size_t)z * B + b) * H + col] = acc[b];
}

// ---------------------------------------------------------------------------
// K3: up[z][b][e] = sum_{h in 64-chunk z} qw[b,h] * W_enc[h,e], all b,
// where qw[b,h] = sum_z' qwp[z'][b][h] is reduced inline (stage A).
// grid (E/256=8, UZ=16) = 128 blocks x 256 thr; W_enc read exactly once (8 MB).
// ---------------------------------------------------------------------------
__global__ void k_u2(const float* __restrict__ qwp,
                     const float* __restrict__ W_enc,
                     float* __restrict__ up) {
    __shared__ float qwl[B][64];
    int tid = threadIdx.x;
    int z = blockIdx.y;
    for (int k = tid; k < B * 64; k += 256) {
        int b = k >> 6, j = k & 63;
        float s = 0.f;
        #pragma unroll
        for (int zz = 0; zz < QZ; ++zz)
            s += qwp[((size_t)zz * B + b) * H + z * 64 + j];
        qwl[b][j] = s;
    }
    __syncthreads();
    int col = blockIdx.x * 256 + tid;
    float acc[B];
    #pragma unroll
    for (int b = 0; b < B; ++b) acc[b] = 0.f;
    #pragma unroll 8
    for (int j = 0; j < 64; ++j) {
        float w = W_enc[(size_t)(z * 64 + j) * E + col];
        #pragma unroll
        for (int b = 0; b < B; ++b) acc[b] += qwl[b][j] * w;
    }
    #pragma unroll
    for (int b = 0; b < B; ++b)
        up[((size_t)z * B + b) * E + col] = acc[b];
}

// ---------------------------------------------------------------------------
// K4: u = sum_z up[z].  32 blocks x 256 thr, float4, 16 independent loads.
// ---------------------------------------------------------------------------
__global__ void k_ured(const float* __restrict__ up,
                       float* __restrict__ u) {
    int idx = blockIdx.x * 256 + threadIdx.x;   // float4 index, B*E/4 total
    float4 acc = {0.f, 0.f, 0.f, 0.f};
    #pragma unroll
    for (int z = 0; z < UZ; ++z) {
        float4 p = ((const float4*)up)[(size_t)z * (B * E / 4) + idx];
        acc.x += p.x; acc.y += p.y; acc.z += p.z; acc.w += p.w;
    }
    ((float4*)u)[idx] = acc;
}

// ---------------------------------------------------------------------------
// K5: scores[b,s] = mask ? dot(u[b,:], value[b,s,:]) : -inf   (proven)
// ---------------------------------------------------------------------------
__global__ void k_scores(const float* __restrict__ u,
                         const float* __restrict__ value,
                         const int* __restrict__ mask,
                         float* __restrict__ scores) {
    int b = blockIdx.y;
    int w = threadIdx.x >> 6;
    int lane = threadIdx.x & 63;
    const float4* u4 = (const float4*)(u + (size_t)b * E);
    float4 uu[8];
    #pragma unroll
    for (int i = 0; i < 8; ++i) uu[i] = u4[i * 64 + lane];
    int s0 = blockIdx.x * 16 + w * 4;
    #pragma unroll
    for (int r = 0; r < 4; r += 2) {
        int s = s0 + r;
        const float4* v0 = (const float4*)(value + ((size_t)(b * S + s)) * E);
        const float4* v1 = (const float4*)(value + ((size_t)(b * S + s + 1)) * E);
        float a0 = 0.f, a1 = 0.f;
        #pragma unroll
        for (int i = 0; i < 8; ++i) {
            float4 x0 = v0[i * 64 + lane];
            float4 x1 = v1[i * 64 + lane];
            a0 += x0.x * uu[i].x + x0.y * uu[i].y + x0.z * uu[i].z + x0.w * uu[i].w;
            a1 += x1.x * uu[i].x + x1.y * uu[i].y + x1.z * uu[i].z + x1.w * uu[i].w;
        }
        #pragma unroll
        for (int off = 32; off; off >>= 1) {
            a0 += __shfl_down(a0, off, 64);
            a1 += __shfl_down(a1, off, 64);
        }
        if (lane == 0) {
            scores[b * S + s]     = mask[b * S + s]     ? a0 : -INFINITY;
            scores[b * S + s + 1] = mask[b * S + s + 1] ? a1 : -INFINITY;
        }
    }
}

// ---------------------------------------------------------------------------
// K6: softmax + alphas + context, one block per batch.  (proven)
// Skip bound: alpha <= 1e-8 rows contribute <= 2048*1e-8*max|v| ~ 1e-4
// << 7.75e-2 threshold. Threshold test is block-uniform (LDS value).
// ---------------------------------------------------------------------------
__global__ void k_smctx(const float* __restrict__ scores,
                        const float* __restrict__ value,
                        float* __restrict__ alphas,
                        float* __restrict__ context) {
    __shared__ float sc[S];        // 8KB
    __shared__ float red[256];
    int b = blockIdx.x;
    int tid = threadIdx.x;
    const float* srow = scores + b * S;
    float m = -INFINITY;
    for (int s = tid; s < S; s += 256) {
        float v = srow[s];
        sc[s] = v;
        m = fmaxf(m, v);
    }
    red[tid] = m;
    __syncthreads();
    for (int off = 128; off; off >>= 1) {
        if (tid < off) red[tid] = fmaxf(red[tid], red[tid + off]);
        __syncthreads();
    }
    m = red[0];
    __syncthreads();
    float l = 0.f;
    for (int s = tid; s < S; s += 256) {
        float p = __expf(sc[s] - m);
        sc[s] = p;
        l += p;
    }
    red[tid] = l;
    __syncthreads();
    for (int off = 128; off; off >>= 1) {
        if (tid < off) red[tid] += red[tid + off];
        __syncthreads();
    }
    float lsum = red[0];
    float inv = 1.f / lsum;
    float thresh = 1e-8f * lsum;    // p > thresh  <=>  alpha > 1e-8
    for (int s = tid; s < S; s += 256)
        alphas[b * S + s] = sc[s] * inv;
    __syncthreads();
    float4 acc0 = {0.f, 0.f, 0.f, 0.f}, acc1 = {0.f, 0.f, 0.f, 0.f};
    for (int s = 0; s < S; ++s) {
        float p = sc[s];
        if (p > thresh) {           // block-uniform -> no divergence
            const float4* vrow = (const float4*)(value + (size_t)(b * S + s) * E);
            float4 v0 = vrow[tid];
            float4 v1 = vrow[256 + tid];
            acc0.x += p * v0.x; acc0.y += p * v0.y; acc0.z += p * v0.z; acc0.w += p * v0.w;
            acc1.x += p * v1.x; acc1.y += p * v1.y; acc1.z += p * v1.z; acc1.w += p * v1.w;
        }
    }
    acc0.x *= inv; acc0.y *= inv; acc0.z *= inv; acc0.w *= inv;
    acc1.x *= inv; acc1.y *= inv; acc1.z *= inv; acc1.w *= inv;
    float4* ctx4 = (float4*)(context + (size_t)b * E);
    ctx4[tid] = acc0;
    ctx4[256 + tid] = acc1;
}

// ---------------------------------------------------------------------------
extern "C" void kernel_launch(void* const* d_in, const int* in_sizes, int n_in,
                              void* d_out, int out_size, void* d_ws, size_t ws_size,
                              hipStream_t stream) {
    const float* query = (const float*)d_in[0];   // [B,1,H]
    const float* value = (const float*)d_in[1];   // [B,S,E]
    const int*   mask  = (const int*)d_in[2];     // [B,1,S]
    const float* W_enc = (const float*)d_in[3];   // [H,E]
    const float* W_q   = (const float*)d_in[4];   // [H,H]
    const float* W_bil = (const float*)d_in[5];   // [H,H]

    float* out = (float*)d_out;
    float* context = out;          // [B,1,E]
    float* alphas  = out + B * E;  // [B,1,S]

    float* ws = (float*)d_ws;
    float* u     = ws;                          // B*E
    float* sc_ws = ws + B * E;                  // B*S
    float* qp    = ws + B * E + B * S;          // B*H
    float* qwp   = qp + B * H;                  // QZ*B*H (1 MB)
    float* up    = qwp + (size_t)QZ * B * H;    // UZ*B*E (2 MB)

    // Chain: batch-in-registers, each weight matrix read exactly once
    k_qp  <<<dim3(H / 4), 256, 0, stream>>>(query, W_q, qp);
    k_qw2 <<<dim3(H / 256, QZ), 256, 0, stream>>>(qp, W_bil, qwp);
    k_u2  <<<dim3(E / 256, UZ), 256, 0, stream>>>(qwp, W_enc, up);
    k_ured<<<dim3(B * E / 1024), 256, 0, stream>>>(up, u);

    // Scores (the 268 MB HBM stream)
    k_scores<<<dim3(S / 16, B), 256, 0, stream>>>(u, value, mask, sc_ws);

    // Softmax + alphas + context
    k_smctx<<<dim3(B), 256, 0, stream>>>(sc_ws, value, alphas, context);
}

// Round 10
// 202.484 us; speedup vs baseline: 1.0936x; 1.0936x over previous
//
#include <hip/hip_runtime.h>
#include <hip/hip_bf16.h>
#include <math.h>

// Problem constants
constexpr int B = 16;
constexpr int S = 2048;
constexpr int H = 1024;
constexpr int E = 2048;

constexpr int QPZ = 4;    // q-split for qp partials (chunks of 256)
constexpr int QWZ = 64;   // hp-split for qw partials (chunks of 16)
constexpr int UZ  = 64;   // h-split for u partials (chunks of 16)

// ---------------------------------------------------------------------------
// K1: qpp[z][b][h] = dot(query[b, z*256..+256], W_q[h, z*256..+256])
// grid (H/4=256, QPZ=4) = 1024 blocks x 256 thr. Wave per h-row.
// Query fragment per-lane in REGISTERS (16 float4, coalesced per b).
// W_q read exactly once. 16 batch accumulators, butterfly reduce.
// ---------------------------------------------------------------------------
__global__ void k_qp(const float* __restrict__ query,
                     const float* __restrict__ W_q,
                     float* __restrict__ qpp) {
    int z = blockIdx.y;
    int tid = threadIdx.x, wave = tid >> 6, lane = tid & 63;
    int h = blockIdx.x * 4 + wave;
    int q0 = z * 256 + lane * 4;
    float4 qf[B];
    #pragma unroll
    for (int b = 0; b < B; ++b)
        qf[b] = *(const float4*)(query + b * H + q0);
    float4 w = *(const float4*)(W_q + (size_t)h * H + q0);
    float acc[B];
    #pragma unroll
    for (int b = 0; b < B; ++b)
        acc[b] = w.x * qf[b].x + w.y * qf[b].y + w.z * qf[b].z + w.w * qf[b].w;
    #pragma unroll
    for (int off = 32; off; off >>= 1)
        #pragma unroll
        for (int b = 0; b < B; ++b)
            acc[b] += __shfl_down(acc[b], off, 64);
    if (lane == 0) {
        #pragma unroll
        for (int b = 0; b < B; ++b)
            qpp[((size_t)z * B + b) * H + h] = acc[b];
    }
}

// ---------------------------------------------------------------------------
// K2: qwp[z][b][col] = sum_{j<16} qp[b, z*16+j] * W_bil[z*16+j, col]
// grid (H/256=4, QWZ=64) = 256 blocks x 256 thr.
// Stage A: inline reduce of the 4 qpp partials for this 16-row chunk.
// Stage B: 16 fully-unrolled independent coalesced 1KB weight loads;
// W_bil read exactly once; 16 b-accums; LDS broadcasts are free.
// ---------------------------------------------------------------------------
__global__ void k_qw(const float* __restrict__ qpp,
                     const float* __restrict__ W_bil,
                     float* __restrict__ qwp) {
    __shared__ float qpl[B][16];
    int z = blockIdx.y;
    int tid = threadIdx.x;
    if (tid < B * 16) {
        int b = tid >> 4, j = tid & 15;
        float s = 0.f;
        #pragma unroll
        for (int zz = 0; zz < QPZ; ++zz)
            s += qpp[((size_t)zz * B + b) * H + z * 16 + j];
        qpl[b][j] = s;
    }
    __syncthreads();
    int col = blockIdx.x * 256 + tid;
    float acc[B];
    #pragma unroll
    for (int b = 0; b < B; ++b) acc[b] = 0.f;
    #pragma unroll
    for (int j = 0; j < 16; ++j) {
        float w = W_bil[(size_t)(z * 16 + j) * H + col];
        #pragma unroll
        for (int b = 0; b < B; ++b) acc[b] += qpl[b][j] * w;
    }
    #pragma unroll
    for (int b = 0; b < B; ++b)
        qwp[((size_t)z * B + b) * H + col] = acc[b];
}

// ---------------------------------------------------------------------------
// K3: qw = sum_z qwp[z].  64 blocks x 256 thr; 64 independent coalesced loads.
// ---------------------------------------------------------------------------
__global__ void k_qwred(const float* __restrict__ qwp,
                        float* __restrict__ qw) {
    int idx = blockIdx.x * 256 + threadIdx.x;   // over B*H
    float acc = 0.f;
    #pragma unroll
    for (int z = 0; z < QWZ; ++z)
        acc += qwp[(size_t)z * (B * H) + idx];
    qw[idx] = acc;
}

// ---------------------------------------------------------------------------
// K4: up[z][b][col] = sum_{j<16} qw[b, z*16+j] * W_enc[z*16+j, col]
// grid (E/256=8, UZ=64) = 512 blocks x 256 thr. W_enc read exactly once.
// ---------------------------------------------------------------------------
__global__ void k_u(const float* __restrict__ qw,
                    const float* __restrict__ W_enc,
                    float* __restrict__ up) {
    __shared__ float qwl[B][16];
    int z = blockIdx.y;
    int tid = threadIdx.x;
    if (tid < B * 16) {
        int b = tid >> 4, j = tid & 15;
        qwl[b][j] = qw[b * H + z * 16 + j];
    }
    __syncthreads();
    int col = blockIdx.x * 256 + tid;
    float acc[B];
    #pragma unroll
    for (int b = 0; b < B; ++b) acc[b] = 0.f;
    #pragma unroll
    for (int j = 0; j < 16; ++j) {
        float w = W_enc[(size_t)(z * 16 + j) * E + col];
        #pragma unroll
        for (int b = 0; b < B; ++b) acc[b] += qwl[b][j] * w;
    }
    #pragma unroll
    for (int b = 0; b < B; ++b)
        up[((size_t)z * B + b) * E + col] = acc[b];
}

// ---------------------------------------------------------------------------
// K5: u = sum_z up[z].  128 blocks x 256 thr; 64 independent coalesced loads.
// ---------------------------------------------------------------------------
__global__ void k_ured(const float* __restrict__ up,
                       float* __restrict__ u) {
    int idx = blockIdx.x * 256 + threadIdx.x;   // over B*E
    float acc = 0.f;
    #pragma unroll
    for (int z = 0; z < UZ; ++z)
        acc += up[(size_t)z * (B * E) + idx];
    u[idx] = acc;
}

// ---------------------------------------------------------------------------
// K6: scores[b,s] = mask ? dot(u[b,:], value[b,s,:]) : -inf   (proven)
// ---------------------------------------------------------------------------
__global__ void k_scores(const float* __restrict__ u,
                         const float* __restrict__ value,
                         const int* __restrict__ mask,
                         float* __restrict__ scores) {
    int b = blockIdx.y;
    int w = threadIdx.x >> 6;
    int lane = threadIdx.x & 63;
    const float4* u4 = (const float4*)(u + (size_t)b * E);
    float4 uu[8];
    #pragma unroll
    for (int i = 0; i < 8; ++i) uu[i] = u4[i * 64 + lane];
    int s0 = blockIdx.x * 16 + w * 4;
    #pragma unroll
    for (int r = 0; r < 4; r += 2) {
        int s = s0 + r;
        const float4* v0 = (const float4*)(value + ((size_t)(b * S + s)) * E);
        const float4* v1 = (const float4*)(value + ((size_t)(b * S + s + 1)) * E);
        float a0 = 0.f, a1 = 0.f;
        #pragma unroll
        for (int i = 0; i < 8; ++i) {
            float4 x0 = v0[i * 64 + lane];
            float4 x1 = v1[i * 64 + lane];
            a0 += x0.x * uu[i].x + x0.y * uu[i].y + x0.z * uu[i].z + x0.w * uu[i].w;
            a1 += x1.x * uu[i].x + x1.y * uu[i].y + x1.z * uu[i].z + x1.w * uu[i].w;
        }
        #pragma unroll
        for (int off = 32; off; off >>= 1) {
            a0 += __shfl_down(a0, off, 64);
            a1 += __shfl_down(a1, off, 64);
        }
        if (lane == 0) {
            scores[b * S + s]     = mask[b * S + s]     ? a0 : -INFINITY;
            scores[b * S + s + 1] = mask[b * S + s + 1] ? a1 : -INFINITY;
        }
    }
}

// ---------------------------------------------------------------------------
// K7: softmax + alphas + context, one block per batch.  (proven)
// Skip bound: alpha <= 1e-8 rows contribute <= 2048*1e-8*max|v| ~ 1e-4
// << 7.75e-2 threshold. Threshold test is block-uniform (LDS value).
// ---------------------------------------------------------------------------
__global__ void k_smctx(const float* __restrict__ scores,
                        const float* __restrict__ value,
                        float* __restrict__ alphas,
                        float* __restrict__ context) {
    __shared__ float sc[S];        // 8KB
    __shared__ float red[256];
    int b = blockIdx.x;
    int tid = threadIdx.x;
    const float* srow = scores + b * S;
    float m = -INFINITY;
    for (int s = tid; s < S; s += 256) {
        float v = srow[s];
        sc[s] = v;
        m = fmaxf(m, v);
    }
    red[tid] = m;
    __syncthreads();
    for (int off = 128; off; off >>= 1) {
        if (tid < off) red[tid] = fmaxf(red[tid], red[tid + off]);
        __syncthreads();
    }
    m = red[0];
    __syncthreads();
    float l = 0.f;
    for (int s = tid; s < S; s += 256) {
        float p = __expf(sc[s] - m);
        sc[s] = p;
        l += p;
    }
    red[tid] = l;
    __syncthreads();
    for (int off = 128; off; off >>= 1) {
        if (tid < off) red[tid] += red[tid + off];
        __syncthreads();
    }
    float lsum = red[0];
    float inv = 1.f / lsum;
    float thresh = 1e-8f * lsum;    // p > thresh  <=>  alpha > 1e-8
    for (int s = tid; s < S; s += 256)
        alphas[b * S + s] = sc[s] * inv;
    __syncthreads();
    float4 acc0 = {0.f, 0.f, 0.f, 0.f}, acc1 = {0.f, 0.f, 0.f, 0.f};
    for (int s = 0; s < S; ++s) {
        float p = sc[s];
        if (p > thresh) {           // block-uniform -> no divergence
            const float4* vrow = (const float4*)(value + (size_t)(b * S + s) * E);
            float4 v0 = vrow[tid];
            float4 v1 = vrow[256 + tid];
            acc0.x += p * v0.x; acc0.y += p * v0.y; acc0.z += p * v0.z; acc0.w += p * v0.w;
            acc1.x += p * v1.x; acc1.y += p * v1.y; acc1.z += p * v1.z; acc1.w += p * v1.w;
        }
    }
    acc0.x *= inv; acc0.y *= inv; acc0.z *= inv; acc0.w *= inv;
    acc1.x *= inv; acc1.y *= inv; acc1.z *= inv; acc1.w *= inv;
    float4* ctx4 = (float4*)(context + (size_t)b * E);
    ctx4[tid] = acc0;
    ctx4[256 + tid] = acc1;
}

// ---------------------------------------------------------------------------
extern "C" void kernel_launch(void* const* d_in, const int* in_sizes, int n_in,
                              void* d_out, int out_size, void* d_ws, size_t ws_size,
                              hipStream_t stream) {
    const float* query = (const float*)d_in[0];   // [B,1,H]
    const float* value = (const float*)d_in[1];   // [B,S,E]
    const int*   mask  = (const int*)d_in[2];     // [B,1,S]
    const float* W_enc = (const float*)d_in[3];   // [H,E]
    const float* W_q   = (const float*)d_in[4];   // [H,H]
    const float* W_bil = (const float*)d_in[5];   // [H,H]

    float* out = (float*)d_out;
    float* context = out;          // [B,1,E]
    float* alphas  = out + B * E;  // [B,1,S]

    float* ws = (float*)d_ws;
    float* u     = ws;                              // B*E
    float* sc_ws = u + B * E;                       // B*S
    float* qpp   = sc_ws + B * S;                   // QPZ*B*H  (256 KB)
    float* qwp   = qpp + (size_t)QPZ * B * H;       // QWZ*B*H  (4 MB)
    float* qw    = qwp + (size_t)QWZ * B * H;       // B*H
    float* up    = qw + B * H;                      // UZ*B*E   (8 MB)

    // Chain: zero weight redundancy + >=256 blocks + deep unrolled load ILP
    k_qp   <<<dim3(H / 4, QPZ), 256, 0, stream>>>(query, W_q, qpp);
    k_qw   <<<dim3(H / 256, QWZ), 256, 0, stream>>>(qpp, W_bil, qwp);
    k_qwred<<<dim3(B * H / 256), 256, 0, stream>>>(qwp, qw);
    k_u    <<<dim3(E / 256, UZ), 256, 0, stream>>>(qw, W_enc, up);
    k_ured <<<dim3(B * E / 256), 256, 0, stream>>>(up, u);

    // Scores (the 268 MB HBM stream)
    k_scores<<<dim3(S / 16, B), 256, 0, stream>>>(u, value, mask, sc_ws);

    // Softmax + alphas + context
    k_smctx<<<dim3(B), 256, 0, stream>>>(sc_ws, value, alphas, context);
}